// Round 9
// baseline (395.074 us; speedup 1.0000x reference)
//
#include <hip/hip_runtime.h>
#include <hip/hip_bf16.h>
#include <math.h>

#define TT 365
#define BT 23360
#define NPOS 425

typedef __hip_bfloat16 bf16;
typedef __attribute__((ext_vector_type(8))) short s16x8;
typedef __attribute__((ext_vector_type(4))) float f32x4;

__device__ __forceinline__ float b2f(bf16 v) { return __bfloat162float(v); }
__device__ __forceinline__ bf16  f2b(float v) { return __float2bfloat16(v); }
__device__ __forceinline__ float u2f(unsigned u) { return __uint_as_float(u); }
__device__ __forceinline__ short f2bs(float v) { bf16 h = __float2bfloat16(v); return *reinterpret_cast<short*>(&h); }
__device__ __forceinline__ void unpack8(uint4 raw, float* v) {
    v[0] = u2f(raw.x << 16); v[1] = u2f(raw.x & 0xffff0000u);
    v[2] = u2f(raw.y << 16); v[3] = u2f(raw.y & 0xffff0000u);
    v[4] = u2f(raw.z << 16); v[5] = u2f(raw.z & 0xffff0000u);
    v[6] = u2f(raw.w << 16); v[7] = u2f(raw.w & 0xffff0000u);
}

// ---------------- prep: zero pooled/esum, split-cast weights, pos table --------------------------
// whi/wlo element offsets: w2@0(8192) w3@8192(32768) wi@40960(65536) wq@106496(32768)
__global__ __launch_bounds__(256) void prep_kernel(
    float* __restrict__ pooled, float* __restrict__ esum,
    const float* __restrict__ w2, const float* __restrict__ w3, const float* __restrict__ wi,
    const float* __restrict__ wq,
    bf16* __restrict__ whi, bf16* __restrict__ wlo, float* __restrict__ tab)
{
    int i = blockIdx.x * 256 + threadIdx.x;
    if (i < 16384) { pooled[i] = 0.f; return; } i -= 16384;
    if (i < 16384) { esum[i] = 0.f; return; }   i -= 16384;
    if (i < 139264) {
        float w;
        if      (i < 8192)   w = w2[i];
        else if (i < 40960)  w = w3[i - 8192];
        else if (i < 106496) w = wi[i - 40960];
        else                 w = wq[i - 106496];
        bf16 h = f2b(w);
        whi[i] = h;
        wlo[i] = f2b(w - b2f(h));
        return;
    } i -= 139264;
    if (i < 108800) {
        int c = i & 255, p = i >> 8;
        float e = (float)(2 * (c >> 1)) * (1.f / 256.f);
        float ang = (float)p * exp2f(-e * 9.96578428466209f);   // 1000^-e
        tab[i] = (c & 1) ? cosf(ang) : sinf(ang);
    }
}

// ---------------- reduce per-rowblock partials -> BN coefs (sc, sh) ----------------
__global__ __launch_bounds__(512) void red_kernel(
    const float* __restrict__ partials, const float* __restrict__ g,
    const float* __restrict__ beta, float* __restrict__ coef, int Ncols)
{
    __shared__ float sums[512];
    const int t = threadIdx.x;
    const int c = t & 255;
    const int off = (t >> 8) << 8;   // 0 or 256
    float s = 0.f;
    if (c < Ncols) {
        const float* p = partials + off + c;
        for (int r = 0; r < 365; ++r) s += p[r * 512];
    }
    sums[t] = s;
    __syncthreads();
    if (t < Ncols) {
        float mu = sums[t] * (1.f / (float)BT);
        float var = sums[256 + t] * (1.f / (float)BT) - mu * mu;
        float sc = rsqrtf(var + 1e-5f) * g[t];
        coef[t] = sc;
        coef[256 + t] = beta[t] - mu * sc;
    }
}

// ---------------- L1 GEMM (K=10, f32 A): Y[M,64](bf16) = x @ w1^T + b1; partial BN stats --------
__global__ __launch_bounds__(256) void gemm_l1_kernel(
    const float* __restrict__ x,
    const float* __restrict__ W, const float* __restrict__ bias,
    bf16* __restrict__ Y, float* __restrict__ partials)
{
    const int t  = threadIdx.x;
    const int tx = t & 15, ty = t >> 4;
    const int row0 = blockIdx.x * 64;
    __shared__ float As[64][17];
    __shared__ float Ws[16][65];
    __shared__ float red_s[4][64];
    __shared__ float red_q[4][64];
    float acc[4][4];
#pragma unroll
    for (int rr = 0; rr < 4; ++rr)
#pragma unroll
        for (int cc = 0; cc < 4; ++cc) acc[rr][cc] = 0.f;
#pragma unroll
    for (int i = 0; i < 4; ++i) {
        int idx = t + i * 256, r = idx >> 4, c = idx & 15;
        As[r][c] = (c < 10) ? x[(size_t)(row0 + r) * 10 + c] : 0.f;
    }
#pragma unroll
    for (int i = 0; i < 4; ++i) {
        int idx = t + i * 256, c = idx >> 4, kk = idx & 15;
        Ws[kk][c] = (kk < 10) ? W[(size_t)c * 10 + kk] : 0.f;
    }
    __syncthreads();
#pragma unroll
    for (int kk = 0; kk < 10; ++kk) {
        float a[4];
#pragma unroll
        for (int rr = 0; rr < 4; ++rr) a[rr] = As[ty * 4 + rr][kk];
#pragma unroll
        for (int cc = 0; cc < 4; ++cc) {
            float w = Ws[kk][cc * 16 + tx];
#pragma unroll
            for (int rr = 0; rr < 4; ++rr) acc[rr][cc] = fmaf(a[rr], w, acc[rr][cc]);
        }
    }
    float s_cc[4], q_cc[4];
#pragma unroll
    for (int cc = 0; cc < 4; ++cc) { s_cc[cc] = 0.f; q_cc[cc] = 0.f; }
#pragma unroll
    for (int rr = 0; rr < 4; ++rr) {
        int row = row0 + ty * 4 + rr;
#pragma unroll
        for (int cc = 0; cc < 4; ++cc) {
            int col = cc * 16 + tx;
            float v = acc[rr][cc] + bias[col];
            Y[(size_t)row * 64 + col] = f2b(v);
            s_cc[cc] += v; q_cc[cc] += v * v;
        }
    }
    int w = t >> 6;
#pragma unroll
    for (int cc = 0; cc < 4; ++cc) {
        float s = s_cc[cc], q = q_cc[cc];
        s += __shfl_xor(s, 16); q += __shfl_xor(q, 16);
        s += __shfl_xor(s, 32); q += __shfl_xor(q, 32);
        if ((t & 63) < 16) { red_s[w][cc * 16 + tx] = s; red_q[w][cc * 16 + tx] = q; }
    }
    __syncthreads();
    if (t < 64) {
        float* pr = partials + (size_t)blockIdx.x * 512;
        pr[t]       = red_s[0][t] + red_s[1][t] + red_s[2][t] + red_s[3][t];
        pr[256 + t] = red_q[0][t] + red_q[1][t] + red_q[2][t] + red_q[3][t];
    }
}

// ---------------- MFMA GEMM, LDS-staged W, fused A transforms, partials (no atomics) ------------
// MODE 0: A raw. MODE 1: A = relu(y*sc+sh). MODE 2: + se[b,k].
template<int MODE, int K>
__global__ __launch_bounds__(256) void mfma_gemm(
    const bf16* __restrict__ A,
    const bf16* __restrict__ Whi, const bf16* __restrict__ Wlo,
    const float* __restrict__ bias,
    bf16* __restrict__ Y, int ldY, float* __restrict__ partials,
    const float* __restrict__ coef, const float* __restrict__ sebuf)
{
    constexpr int KC = (K > 128) ? 128 : K;
    __shared__ s16x8 Wl[2][KC / 8][64];
    __shared__ float red_s[4][64];
    __shared__ float red_q[4][64];
    __shared__ float scb[MODE ? K : 1];
    __shared__ float shb[MODE ? K : 1];
    const int t = threadIdx.x, wave = t >> 6, lane = t & 63;
    const int n16 = lane & 15, quad = lane >> 4;
    const int m0 = blockIdx.x * 64 + wave * 16;
    const int col0 = blockIdx.y * 64;
    const int sc_ = t & 63, skg0 = t >> 6;
    const bf16* gh = Whi + (size_t)(col0 + sc_) * K;
    const bf16* gl = Wlo + (size_t)(col0 + sc_) * K;
#pragma unroll
    for (int kg = skg0; kg < KC / 8; kg += 4) {
        Wl[0][kg][sc_] = *(const s16x8*)(gh + kg * 8);
        Wl[1][kg][sc_] = *(const s16x8*)(gl + kg * 8);
    }
    if (MODE) {
        if (t < K) { scb[t] = coef[t]; shb[t] = coef[256 + t]; }
    }
    __syncthreads();
    const int arow = m0 + n16;
    const float* sev = (MODE == 2) ? (sebuf + (arow / TT) * 256) : nullptr;
    const bf16* Ap = A + (size_t)arow * K + quad * 8;
    s16x8 af[K / 32];
#pragma unroll
    for (int i = 0; i < K / 32; ++i) {
        s16x8 raw = *(const s16x8*)(Ap + i * 32);
        if (MODE) {
            int kb = i * 32 + quad * 8;
#pragma unroll
            for (int j = 0; j < 8; ++j) {
                float y = u2f(((unsigned)(unsigned short)raw[j]) << 16);
                float v = fmaxf(fmaf(y, scb[kb + j], shb[kb + j]), 0.f);
                if (MODE == 2) v += sev[kb + j];
                raw[j] = f2bs(v);
            }
        }
        af[i] = raw;
    }
    f32x4 acc[4];
    f32x4 zero = {0.f, 0.f, 0.f, 0.f};
#pragma unroll
    for (int ct = 0; ct < 4; ++ct) acc[ct] = zero;
#pragma unroll
    for (int kc = 0; kc < K; kc += KC) {
        if (kc) {
            __syncthreads();
#pragma unroll
            for (int kg = skg0; kg < KC / 8; kg += 4) {
                Wl[0][kg][sc_] = *(const s16x8*)(gh + kc + kg * 8);
                Wl[1][kg][sc_] = *(const s16x8*)(gl + kc + kg * 8);
            }
            __syncthreads();
        }
#pragma unroll
        for (int i = 0; i < KC / 32; ++i) {
            const int kgq = i * 4 + quad;
            const s16x8 a = af[(kc >> 5) + i];
#pragma unroll
            for (int ct = 0; ct < 4; ++ct) {
                s16x8 bl = Wl[1][kgq][ct * 16 + n16];
                s16x8 bh = Wl[0][kgq][ct * 16 + n16];
                acc[ct] = __builtin_amdgcn_mfma_f32_16x16x32_bf16(a, bl, acc[ct], 0, 0, 0);
                acc[ct] = __builtin_amdgcn_mfma_f32_16x16x32_bf16(a, bh, acc[ct], 0, 0, 0);
            }
        }
    }
#pragma unroll
    for (int ct = 0; ct < 4; ++ct) {
        int col = col0 + ct * 16 + n16;
        float bv = bias[col];
        float s = 0.f, q = 0.f;
#pragma unroll
        for (int r = 0; r < 4; ++r) {
            float v = acc[ct][r] + bv;
            int row = m0 + quad * 4 + r;
            Y[(size_t)row * ldY + col] = f2b(v);
            s += v; q += v * v;
        }
        s += __shfl_xor(s, 16); q += __shfl_xor(q, 16);
        s += __shfl_xor(s, 32); q += __shfl_xor(q, 32);
        if (quad == 0) { red_s[wave][ct * 16 + n16] = s; red_q[wave][ct * 16 + n16] = q; }
    }
    if (partials) {
        __syncthreads();
        if (t < 64) {
            float* pr = partials + (size_t)blockIdx.x * 512;
            pr[col0 + t]       = red_s[0][t] + red_s[1][t] + red_s[2][t] + red_s[3][t];
            pr[256 + col0 + t] = red_q[0][t] + red_q[1][t] + red_q[2][t] + red_q[3][t];
        }
    }
}

// ---------------- pool partial: pooled[b,f] += sum_rows relu(bn3(Y3)) ----------------
__global__ __launch_bounds__(256) void pool_partial_kernel(
    const bf16* __restrict__ Y3, const float* __restrict__ coef,
    float* __restrict__ pooled)
{
    const int b = blockIdx.x, part = blockIdx.y, t = threadIdx.x;
    const int cg = t & 31, rs = t >> 5;
    __shared__ float scb[256], shb[256];
    __shared__ float pp[8][256];
    scb[t] = coef[t]; shb[t] = coef[256 + t];
    __syncthreads();
    float acc[8] = {0.f,0.f,0.f,0.f,0.f,0.f,0.f,0.f};
    const int r0 = part * 46;
#pragma unroll
    for (int i = 0; i < 6; ++i) {
        int l = rs + i * 8;
        int r = r0 + l;
        if (l < 46 && r < TT) {
            uint4 raw = *(const uint4*)(Y3 + ((size_t)b * TT + r) * 256 + cg * 8);
            float v[8];
            unpack8(raw, v);
#pragma unroll
            for (int j = 0; j < 8; ++j)
                acc[j] += fmaxf(fmaf(v[j], scb[cg * 8 + j], shb[cg * 8 + j]), 0.f);
        }
    }
#pragma unroll
    for (int j = 0; j < 8; ++j) pp[rs][cg * 8 + j] = acc[j];
    __syncthreads();
    float s = 0.f;
#pragma unroll
    for (int r = 0; r < 8; ++r) s += pp[r][t];
    atomicAdd(&pooled[b * 256 + t], s);
}

// ---------------- esum partial ----------------
__global__ __launch_bounds__(256) void esum_kernel(const bf16* __restrict__ e,
                                                   float* __restrict__ esum)
{
    const int b = blockIdx.x, part = blockIdx.y, t = threadIdx.x;
    const int cg = t & 31, rs = t >> 5;
    __shared__ float pp[8][256];
    float acc[8] = {0.f,0.f,0.f,0.f,0.f,0.f,0.f,0.f};
    const int r0 = part * 46;
#pragma unroll
    for (int i = 0; i < 6; ++i) {
        int l = rs + i * 8;
        int r = r0 + l;
        if (l < 46 && r < TT) {
            uint4 raw = *(const uint4*)(e + ((size_t)b * TT + r) * 256 + cg * 8);
            float v[8];
            unpack8(raw, v);
#pragma unroll
            for (int j = 0; j < 8; ++j) acc[j] += v[j];
        }
    }
#pragma unroll
    for (int j = 0; j < 8; ++j) pp[rs][cg * 8 + j] = acc[j];
    __syncthreads();
    float s = 0.f;
#pragma unroll
    for (int r = 0; r < 8; ++r) s += pp[r][t];
    atomicAdd(&esum[b * 256 + t], s);
}

// ---------------- SE MLP ----------------
__global__ __launch_bounds__(256) void se_mlp_kernel(const float* __restrict__ pooled,
                                                     const float* __restrict__ ws1,
                                                     const float* __restrict__ ws2,
                                                     float* __restrict__ se) {
    int b = blockIdx.x, f = threadIdx.x;
    __shared__ float pl[256];
    __shared__ float hidden[16];
    float p = pooled[b * 256 + f] * (1.f / (float)TT);
    pl[f] = p;
    __syncthreads();
    if (f < 16) {
        float h = 0.f;
        for (int k2 = 0; k2 < 256; ++k2) h = fmaf(pl[k2], ws1[f * 256 + k2], h);
        hidden[f] = fmaxf(h, 0.f);
    }
    __syncthreads();
    float a = 0.f;
    for (int k2 = 0; k2 < 16; ++k2) a = fmaf(hidden[k2], ws2[f * 16 + k2], a);
    a = 1.f / (1.f + expf(-a));
    se[b * 256 + f] = a * p;
}

// ---------------- BN(coef) + ReLU + positional add, 8 elems/thread ----------------
__global__ __launch_bounds__(256) void bnrelu8_kernel(
    const bf16* __restrict__ Y, const float* __restrict__ coef,
    bf16* __restrict__ Out, const float* __restrict__ tab, const int* __restrict__ pos) {
    int i = (blockIdx.x * 256 + threadIdx.x) * 8;
    int col = i & 255, row = i >> 8;
    uint4 raw = *(const uint4*)(Y + i);
    float v[8];
    unpack8(raw, v);
    const float* tr = tab + pos[row] * 256 + col;
    bf16 tmp[8] __attribute__((aligned(16)));
#pragma unroll
    for (int j = 0; j < 8; ++j) {
        float o = fmaf(v[j], coef[col + j], coef[256 + col + j]);
        tmp[j] = f2b(fmaxf(o, 0.f) + tr[j]);
    }
    *(uint4*)(Out + i) = *(const uint4*)tmp;
}

// ---------------- attention: one wave per (b,h); ksum = esum.wk_h^T + T*bk ----------------
__global__ __launch_bounds__(64) void attn_kernel(
    const bf16* __restrict__ q, const bf16* __restrict__ e,
    const float* __restrict__ esum, const float* __restrict__ wk,
    const float* __restrict__ bk, float* __restrict__ yv)
{
    __shared__ float aw[368];
    const int b = blockIdx.x, h = blockIdx.y;
    const int lane = threadIdx.x;
    float4 es = *(const float4*)(esum + b * 256 + lane * 4);
    float ks[8];
#pragma unroll
    for (int d = 0; d < 8; ++d) {
        float4 wv = *(const float4*)(wk + (size_t)(h * 8 + d) * 256 + lane * 4);
        ks[d] = es.x * wv.x + es.y * wv.y + es.z * wv.z + es.w * wv.w;
    }
#pragma unroll
    for (int off = 1; off < 64; off <<= 1)
#pragma unroll
        for (int d = 0; d < 8; ++d) ks[d] += __shfl_xor(ks[d], off);
#pragma unroll
    for (int d = 0; d < 8; ++d) ks[d] += (float)TT * bk[h * 8 + d];
    const float scale = 1.f / (sqrtf(8.f) * (float)TT);
    const bf16* qb = q + (size_t)b * TT * 128 + h * 8;
    float sv[6];
    float m = -1e30f;
#pragma unroll
    for (int i = 0; i < 6; ++i) {
        int r = lane + i * 64;
        float s = -1e30f;
        if (r < TT) {
            uint4 raw = *(const uint4*)(qb + (size_t)r * 128);
            float v[8];
            unpack8(raw, v);
            float dot = 0.f;
#pragma unroll
            for (int j = 0; j < 8; ++j) dot = fmaf(v[j], ks[j], dot);
            s = dot * scale;
        }
        sv[i] = s;
        m = fmaxf(m, s);
    }
#pragma unroll
    for (int off = 1; off < 64; off <<= 1) m = fmaxf(m, __shfl_xor(m, off));
    float sum = 0.f;
#pragma unroll
    for (int i = 0; i < 6; ++i) {
        float ev = (sv[i] > -1e29f) ? expf(sv[i] - m) : 0.f;
        sv[i] = ev; sum += ev;
    }
#pragma unroll
    for (int off = 1; off < 64; off <<= 1) sum += __shfl_xor(sum, off);
    float inv = 1.f / sum;
#pragma unroll
    for (int i = 0; i < 6; ++i) {
        int r = lane + i * 64;
        if (r < TT) aw[r] = sv[i] * inv;
    }
    __syncthreads();
    const int half = lane & 1, rs = lane >> 1;
    float acc[8] = {0.f,0.f,0.f,0.f,0.f,0.f,0.f,0.f};
    const bf16* ebase = e + (size_t)b * TT * 256 + h * 16 + half * 8;
#pragma unroll
    for (int i = 0; i < 12; ++i) {
        int r = rs + i * 32;
        if (r < TT) {
            uint4 raw = *(const uint4*)(ebase + (size_t)r * 256);
            float v[8];
            unpack8(raw, v);
            float a = aw[r];
#pragma unroll
            for (int j = 0; j < 8; ++j) acc[j] = fmaf(a, v[j], acc[j]);
        }
    }
#pragma unroll
    for (int off = 2; off < 64; off <<= 1)
#pragma unroll
        for (int j = 0; j < 8; ++j) acc[j] += __shfl_xor(acc[j], off);
    if (lane < 2) {
        float* op = yv + b * 256 + h * 16 + half * 8;
#pragma unroll
        for (int j = 0; j < 8; ++j) op[j] = acc[j];
    }
}

// ---------------- fused tail: X in LDS, W via wave-uniform (SGPR) loads ----------------
// LDS floats: Xq@0 [64k][65] (4160); Z1t@4160 [128][64] (8192); Z2t@0 [64][64] (4096);
//             Z3t@4160 [32][64] (2048). Total 12352.
__global__ __launch_bounds__(1024) void tail_kernel(
    const float* __restrict__ yv,
    const float* __restrict__ wm, const float* __restrict__ bm,
    const float* __restrict__ gm, const float* __restrict__ em,
    const float* __restrict__ wd1, const float* __restrict__ bd1,
    const float* __restrict__ gd1, const float* __restrict__ ed1,
    const float* __restrict__ wd2, const float* __restrict__ bd2,
    const float* __restrict__ gd2, const float* __restrict__ ed2,
    const float* __restrict__ wc, const float* __restrict__ bc,
    float* __restrict__ out)
{
    __shared__ float lds[12352];
    float* Xq  = lds;
    float* Z1t = lds + 4160;
    float* Z2t = lds;
    float* Z3t = lds + 4160;
    const int t = threadIdx.x;
    const int r = t & 63, cg = t >> 6;
    const int cgu = __builtin_amdgcn_readfirstlane(cg);   // wave-uniform: W/bias via scalar pipe

    // ---- layer 1: 256 -> 128, K in 4 chunks of 64 ----
    float acc1[8] = {0.f,0.f,0.f,0.f,0.f,0.f,0.f,0.f};
    for (int p = 0; p < 4; ++p) {
        __syncthreads();
        for (int i = t; i < 4096; i += 1024) {
            int kk = i & 63, rr = i >> 6;
            Xq[kk * 65 + rr] = yv[rr * 256 + p * 64 + kk];
        }
        __syncthreads();
        const float* wb = wm + (size_t)(cgu * 8) * 256 + p * 64;
#pragma unroll
        for (int kg = 0; kg < 4; ++kg) {
            float xv[16];
#pragma unroll
            for (int j = 0; j < 16; ++j) xv[j] = Xq[(kg * 16 + j) * 65 + r];
#pragma unroll
            for (int c = 0; c < 8; ++c) {
                const float* wp = wb + c * 256 + kg * 16;
#pragma unroll
                for (int j = 0; j < 16; ++j) acc1[c] = fmaf(xv[j], wp[j], acc1[c]);
            }
        }
    }
    float z1v[8];
#pragma unroll
    for (int c = 0; c < 8; ++c) {
        float v = acc1[c] + bm[cgu * 8 + c];
        float s = v, q = v * v;
#pragma unroll
        for (int off = 1; off < 64; off <<= 1) { s += __shfl_xor(s, off); q += __shfl_xor(q, off); }
        float mu = s * (1.f / 64.f), var = q * (1.f / 64.f) - mu * mu;
        z1v[c] = fmaxf((v - mu) * rsqrtf(var + 1e-5f) * gm[cgu * 8 + c] + em[cgu * 8 + c], 0.f);
    }
    __syncthreads();
#pragma unroll
    for (int c = 0; c < 8; ++c) Z1t[(cgu * 8 + c) * 64 + r] = z1v[c];
    __syncthreads();
    // ---- layer 2: 128 -> 64 ----
    float acc2[4] = {0.f, 0.f, 0.f, 0.f};
#pragma unroll
    for (int kg = 0; kg < 8; ++kg) {
        float xv[16];
#pragma unroll
        for (int j = 0; j < 16; ++j) xv[j] = Z1t[(kg * 16 + j) * 64 + r];
#pragma unroll
        for (int c = 0; c < 4; ++c) {
            const float* wp = wd1 + (size_t)(cgu * 4 + c) * 128 + kg * 16;
#pragma unroll
            for (int j = 0; j < 16; ++j) acc2[c] = fmaf(xv[j], wp[j], acc2[c]);
        }
    }
    float z2v[4];
#pragma unroll
    for (int c = 0; c < 4; ++c) {
        float v = acc2[c] + bd1[cgu * 4 + c];
        float s = v, q = v * v;
#pragma unroll
        for (int off = 1; off < 64; off <<= 1) { s += __shfl_xor(s, off); q += __shfl_xor(q, off); }
        float mu = s * (1.f / 64.f), var = q * (1.f / 64.f) - mu * mu;
        z2v[c] = fmaxf((v - mu) * rsqrtf(var + 1e-5f) * gd1[cgu * 4 + c] + ed1[cgu * 4 + c], 0.f);
    }
    __syncthreads();   // all Z1t reads done before overwriting Z2t/Z3t regions
#pragma unroll
    for (int c = 0; c < 4; ++c) Z2t[(cgu * 4 + c) * 64 + r] = z2v[c];
    __syncthreads();
    // ---- layer 3: 64 -> 32 ----
    float acc3[2] = {0.f, 0.f};
#pragma unroll
    for (int kg = 0; kg < 4; ++kg) {
        float xv[16];
#pragma unroll
        for (int j = 0; j < 16; ++j) xv[j] = Z2t[(kg * 16 + j) * 64 + r];
#pragma unroll
        for (int c = 0; c < 2; ++c) {
            const float* wp = wd2 + (size_t)(cgu * 2 + c) * 64 + kg * 16;
#pragma unroll
            for (int j = 0; j < 16; ++j) acc3[c] = fmaf(xv[j], wp[j], acc3[c]);
        }
    }
#pragma unroll
    for (int c = 0; c < 2; ++c) {
        float v = acc3[c] + bd2[cgu * 2 + c];
        float s = v, q = v * v;
#pragma unroll
        for (int off = 1; off < 64; off <<= 1) { s += __shfl_xor(s, off); q += __shfl_xor(q, off); }
        float mu = s * (1.f / 64.f), var = q * (1.f / 64.f) - mu * mu;
        Z3t[(cgu * 2 + c) * 64 + r] = fmaxf((v - mu) * rsqrtf(var + 1e-5f) * gd2[cgu * 2 + c] + ed2[cgu * 2 + c], 0.f);
    }
    __syncthreads();
    // ---- classifier ----
    if (t < 640) {
        int rr = t / 10, c = t % 10;
        float s = bc[c];
#pragma unroll
        for (int kk = 0; kk < 32; ++kk) s = fmaf(Z3t[kk * 64 + rr], wc[c * 32 + kk], s);
        out[t] = s;
    }
}

// ---------------- launch ----------------

extern "C" void kernel_launch(void* const* d_in, const int* in_sizes, int n_in,
                              void* d_out, int out_size, void* d_ws, size_t ws_size,
                              hipStream_t stream) {
    (void)in_sizes; (void)n_in; (void)out_size; (void)ws_size;
    const float* x  = (const float*)d_in[0];
    const int* pos  = (const int*)d_in[1];
    const float *w1 = (const float*)d_in[2],  *b1 = (const float*)d_in[3],
                *g1 = (const float*)d_in[4],  *e1 = (const float*)d_in[5];
    const float *w2 = (const float*)d_in[6],  *b2 = (const float*)d_in[7],
                *g2 = (const float*)d_in[8],  *e2 = (const float*)d_in[9];
    const float *w3 = (const float*)d_in[10], *b3 = (const float*)d_in[11],
                *g3 = (const float*)d_in[12], *e3 = (const float*)d_in[13];
    const float *ws1 = (const float*)d_in[14], *ws2 = (const float*)d_in[15];
    const float *wi = (const float*)d_in[16], *bi = (const float*)d_in[17],
                *gi = (const float*)d_in[18], *ei = (const float*)d_in[19];
    const float *wk = (const float*)d_in[20], *bk = (const float*)d_in[21];   // k before q!
    const float *wq = (const float*)d_in[22], *bq = (const float*)d_in[23];
    const float *wm = (const float*)d_in[24], *bm = (const float*)d_in[25],
                *gm = (const float*)d_in[26], *em = (const float*)d_in[27];
    const float *wd1 = (const float*)d_in[28], *bd1 = (const float*)d_in[29],
                *gd1 = (const float*)d_in[30], *ed1 = (const float*)d_in[31];
    const float *wd2 = (const float*)d_in[32], *bd2 = (const float*)d_in[33],
                *gd2 = (const float*)d_in[34], *ed2 = (const float*)d_in[35];
    const float *wc = (const float*)d_in[36], *bc = (const float*)d_in[37];
    float* out = (float*)d_out;

    char* w8 = (char*)d_ws;
    bf16*  actA   = (bf16*)(w8);                    // 11,960,320
    bf16*  actB   = (bf16*)(w8 + 11960320);         // 11,960,320
    bf16*  whi    = (bf16*)(w8 + 23920640);         //    278,528
    bf16*  wlo    = (bf16*)(w8 + 24199168);         //    278,528
    float* tab    = (float*)(w8 + 24477696);        //    435,200
    float* parts  = (float*)(w8 + 24912896);        //    747,520 (365 x 512)
    float* coef   = (float*)(w8 + 25660416);        //      8,192 (4 x 512)
    float* pooled = (float*)(w8 + 25668608);        //     65,536
    float* sebuf  = (float*)(w8 + 25734144);        //     65,536
    float* esum   = (float*)(w8 + 25799680);        //     65,536
    float* yvb    = (float*)(w8 + 25865216);        //     65,536

    prep_kernel<<<1097, 256, 0, stream>>>(pooled, esum, w2, w3, wi, wq, whi, wlo, tab);
    // L1: 10 -> 64 -> Y1 = actB, partials -> coef1
    gemm_l1_kernel<<<365, 256, 0, stream>>>(x, w1, b1, actB, parts);
    red_kernel<<<1, 512, 0, stream>>>(parts, g1, e1, coef, 64);
    // L2: 64 -> 128 -> Y2 = actA, partials -> coef2
    mfma_gemm<1, 64><<<dim3(365, 2), 256, 0, stream>>>(actB, whi, wlo, b2,
                                                       actA, 128, parts, coef, nullptr);
    red_kernel<<<1, 512, 0, stream>>>(parts, g2, e2, coef + 512, 128);
    // L3: 128 -> 256 -> Y3 = actB, partials -> coef3
    mfma_gemm<1, 128><<<dim3(365, 4), 256, 0, stream>>>(actA, whi + 8192, wlo + 8192, b3,
                                                        actB, 256, parts, coef + 512, nullptr);
    red_kernel<<<1, 512, 0, stream>>>(parts, g3, e3, coef + 1024, 256);
    // pool (fused BN3+relu) -> pooled; SE MLP -> sebuf
    pool_partial_kernel<<<dim3(64, 8), 256, 0, stream>>>(actB, coef + 1024, pooled);
    se_mlp_kernel<<<64, 256, 0, stream>>>(pooled, ws1, ws2, sebuf);
    // inconv (fused BN3+relu+SE residual on A) -> Yi = actA, partials -> coef4
    mfma_gemm<2, 256><<<dim3(365, 4), 256, 0, stream>>>(actB, whi + 40960, wlo + 40960, bi,
                                                        actA, 256, parts, coef + 1024, sebuf);
    red_kernel<<<1, 512, 0, stream>>>(parts, gi, ei, coef + 1536, 256);
    // bn_i + relu + PE -> e = actB
    bnrelu8_kernel<<<BT * 256 / 2048, 256, 0, stream>>>(actA, coef + 1536, actB, tab, pos);
    // esum over e
    esum_kernel<<<dim3(64, 8), 256, 0, stream>>>(actB, esum);
    // q projection: 256 -> 128 -> q = actA
    mfma_gemm<0, 256><<<dim3(365, 2), 256, 0, stream>>>(actB, whi + 106496, wlo + 106496, bq,
                                                        actA, 128, nullptr, nullptr, nullptr);
    // attention
    attn_kernel<<<dim3(64, 16), 64, 0, stream>>>(actA, actB, esum, wk, bk, yvb);
    // fused tail
    tail_kernel<<<1, 1024, 0, stream>>>(yvb, wm, bm, gm, em, wd1, bd1, gd1, ed1,
                                        wd2, bd2, gd2, ed2, wc, bc, out);
}